// Round 12
// baseline (143.788 us; speedup 1.0000x reference)
//
#include <hip/hip_runtime.h>
#include <hip/hip_cooperative_groups.h>
#include <math.h>

namespace cgx = cooperative_groups;

#define POOLED 7
#define SCALE 0.0625f
#define C_ 256
#define H_ 56
#define W_ 56
#define S_ (H_ * W_)   // 3136
#define NCELL 49

typedef _Float16 f16x4 __attribute__((ext_vector_type(4)));

__device__ __forceinline__ f16x4 max4h(f16x4 a, f16x4 b) {
    f16x4 r;
    r[0] = a[0] > b[0] ? a[0] : b[0];
    r[1] = a[1] > b[1] ? a[1] : b[1];
    r[2] = a[2] > b[2] ? a[2] : b[2];
    r[3] = a[3] > b[3] ? a[3] : b[3];
    return r;
}

// ================= Single cooperative kernel: transpose + grid.sync + pool =================
// Phase 1: 784 tiles (64s x 64c x 4b) grid-strided; NCHW fp32 -> NHWC fp16.
// Phase 2: 3328 (n, cellgroup) units grid-strided, XCD-swizzled; 4 waves pool
//          4 cells; LDS-staged coalesced output write (verbatim R11 logic).
__global__ __launch_bounds__(256, 8) void fused_kernel(
    const float* __restrict__ feat, const float* __restrict__ rois,
    _Float16* __restrict__ t, float* __restrict__ out, int nblocks)
{
    __shared__ union {
        float tile[64][65];
        float stage[4][257];
    } sh;

    int tid = threadIdx.x;

    // ---------- Phase 1: NCHW fp32 -> NHWC fp16 ----------
    for (int v = blockIdx.x; v < 784; v += nblocks) {
        int b     = v / 196;
        int rem   = v % 196;
        int cbase = (rem / 49) * 64;
        int sbase = (rem % 49) * 64;
        const float* s0 = feat + (size_t)b * C_ * S_;
        _Float16*    d0 = t    + (size_t)b * S_ * C_;

        int si = tid & 15;          // s-quad
        int ci = tid >> 4;          // 0..15
        #pragma unroll
        for (int p = 0; p < 4; ++p) {
            int c = ci + 16 * p;
            float4 vv = *(const float4*)(s0 + (size_t)(cbase + c) * S_ + sbase + 4 * si);
            sh.tile[4 * si + 0][c] = vv.x;
            sh.tile[4 * si + 1][c] = vv.y;
            sh.tile[4 * si + 2][c] = vv.z;
            sh.tile[4 * si + 3][c] = vv.w;
        }
        __syncthreads();
        int cj = tid & 15;          // c-quad
        int sj = tid >> 4;          // 0..15
        #pragma unroll
        for (int p = 0; p < 4; ++p) {
            int s = sj + 16 * p;
            f16x4 pk;
            pk[0] = (_Float16)sh.tile[s][4 * cj + 0];
            pk[1] = (_Float16)sh.tile[s][4 * cj + 1];
            pk[2] = (_Float16)sh.tile[s][4 * cj + 2];
            pk[3] = (_Float16)sh.tile[s][4 * cj + 3];
            *(f16x4*)(d0 + (size_t)(sbase + s) * C_ + cbase + 4 * cj) = pk;
        }
        __syncthreads();
    }

    cgx::this_grid().sync();

    // ---------- Phase 2: pool + output write ----------
    int wv   = tid >> 6;
    int lane = tid & 63;

    for (int u = blockIdx.x; u < 3328; u += nblocks) {
        int swz  = (u & 7) * 416 + (u >> 3);   // bijective XCD chunking (u, u+2048 share u&7)
        int n    = swz / 13;
        int cg   = swz % 13;
        int cell = cg * 4 + wv;

        const float* r = rois + n * 5;
        int b  = (int)r[0];
        int x1 = (int)(r[1] * SCALE);
        int y1 = (int)(r[2] * SCALE);
        int x2 = (int)(r[3] * SCALE);
        int y2 = (int)(r[4] * SCALE);
        int rh = y2 - y1 + 1;
        int rw = x2 - x1 + 1;

        if (cell < NCELL) {
            int ph = cell / POOLED;
            int pw = cell % POOLED;
            int hs = y1 + (ph * rh) / POOLED;
            int he = y1 + ((ph + 1) * rh + POOLED - 1) / POOLED;
            int ws = x1 + (pw * rw) / POOLED;
            int we = x1 + ((pw + 1) * rw + POOLED - 1) / POOLED;
            int nh = he - hs;
            int nw = we - ws;

            const f16x4* p0 = (const f16x4*)(t + (size_t)b * S_ * C_) + lane
                              + (size_t)(hs * W_ + ws) * 64;

            const _Float16 NEGV = (_Float16)(-65504.0f);
            f16x4 a0 = {NEGV, NEGV, NEGV, NEGV};
            f16x4 a1 = a0, a2 = a0, a3 = a0, a4 = a0, a5 = a0, a6 = a0, a7 = a0;

            for (int h = 0; h < nh; h += 2) {
                int h1 = (h + 1 < nh) ? h + 1 : h;
                const f16x4* hp0 = p0 + (size_t)h  * (W_ * 64);
                const f16x4* hp1 = p0 + (size_t)h1 * (W_ * 64);
                for (int w = 0; w < nw; w += 4) {
                    int w1 = (w + 1 < nw) ? w + 1 : w;
                    int w2 = (w + 2 < nw) ? w + 2 : w;
                    int w3 = (w + 3 < nw) ? w + 3 : w;
                    a0 = max4h(a0, hp0[(size_t)w  * 64]);
                    a1 = max4h(a1, hp0[(size_t)w1 * 64]);
                    a2 = max4h(a2, hp0[(size_t)w2 * 64]);
                    a3 = max4h(a3, hp0[(size_t)w3 * 64]);
                    a4 = max4h(a4, hp1[(size_t)w  * 64]);
                    a5 = max4h(a5, hp1[(size_t)w1 * 64]);
                    a6 = max4h(a6, hp1[(size_t)w2 * 64]);
                    a7 = max4h(a7, hp1[(size_t)w3 * 64]);
                }
            }
            f16x4 m = max4h(max4h(max4h(a0, a1), max4h(a2, a3)),
                            max4h(max4h(a4, a5), max4h(a6, a7)));

            sh.stage[wv][4 * lane + 0] = (float)m[0];
            sh.stage[wv][4 * lane + 1] = (float)m[1];
            sh.stage[wv][4 * lane + 2] = (float)m[2];
            sh.stage[wv][4 * lane + 3] = (float)m[3];
        }
        __syncthreads();

        float* dst = out + (size_t)n * C_ * NCELL + cg * 4;
        if (cg < 12) {
            #pragma unroll
            for (int k = 0; k < 4; ++k) {
                int f = tid + 256 * k;
                int c = f >> 2, j = f & 3;
                dst[(size_t)c * NCELL + j] = sh.stage[j][c];
            }
        } else {
            dst[(size_t)tid * NCELL] = sh.stage[0][tid];
        }
        __syncthreads();
    }
}

// ================= Fallback path (R11 two-kernel, proven at 31.4 us) =================
__global__ __launch_bounds__(1024) void nhwc_kernel(
    const float* __restrict__ src, _Float16* __restrict__ dst)
{
    __shared__ float tile[64][65];
    int b = blockIdx.z;
    int sbase = blockIdx.x * 64;
    int cbase = blockIdx.y * 64;
    int tid = threadIdx.x;

    const float* s0 = src + (size_t)b * C_ * S_;
    _Float16* d0 = dst + (size_t)b * S_ * C_;

    {
        int si = tid & 15;
        int c  = tid >> 4;
        float4 v = *(const float4*)(s0 + (size_t)(cbase + c) * S_ + sbase + 4 * si);
        tile[4 * si + 0][c] = v.x;
        tile[4 * si + 1][c] = v.y;
        tile[4 * si + 2][c] = v.z;
        tile[4 * si + 3][c] = v.w;
    }
    __syncthreads();
    {
        int cj = tid & 15;
        int s  = tid >> 4;
        f16x4 pk;
        pk[0] = (_Float16)tile[s][4 * cj + 0];
        pk[1] = (_Float16)tile[s][4 * cj + 1];
        pk[2] = (_Float16)tile[s][4 * cj + 2];
        pk[3] = (_Float16)tile[s][4 * cj + 3];
        *(f16x4*)(d0 + (size_t)(sbase + s) * C_ + cbase + 4 * cj) = pk;
    }
}

__global__ __launch_bounds__(256) void pool_fused_kernel(
    const _Float16* __restrict__ t, const float* __restrict__ rois,
    float* __restrict__ out)
{
    __shared__ float stage[4][257];
    int b0   = blockIdx.x;
    int swz  = (b0 & 7) * 416 + (b0 >> 3);
    int n    = swz / 13;
    int cg   = swz % 13;
    int wv   = threadIdx.x >> 6;
    int lane = threadIdx.x & 63;
    int cell = cg * 4 + wv;

    const float* r = rois + n * 5;
    int b  = (int)r[0];
    int x1 = (int)(r[1] * SCALE);
    int y1 = (int)(r[2] * SCALE);
    int x2 = (int)(r[3] * SCALE);
    int y2 = (int)(r[4] * SCALE);
    int rh = y2 - y1 + 1;
    int rw = x2 - x1 + 1;

    if (cell < NCELL) {
        int ph = cell / POOLED;
        int pw = cell % POOLED;
        int hs = y1 + (ph * rh) / POOLED;
        int he = y1 + ((ph + 1) * rh + POOLED - 1) / POOLED;
        int ws = x1 + (pw * rw) / POOLED;
        int we = x1 + ((pw + 1) * rw + POOLED - 1) / POOLED;
        int nh = he - hs;
        int nw = we - ws;

        const f16x4* p0 = (const f16x4*)(t + (size_t)b * S_ * C_) + lane
                          + (size_t)(hs * W_ + ws) * 64;

        const _Float16 NEGV = (_Float16)(-65504.0f);
        f16x4 a0 = {NEGV, NEGV, NEGV, NEGV};
        f16x4 a1 = a0, a2 = a0, a3 = a0, a4 = a0, a5 = a0, a6 = a0, a7 = a0;

        for (int h = 0; h < nh; h += 2) {
            int h1 = (h + 1 < nh) ? h + 1 : h;
            const f16x4* hp0 = p0 + (size_t)h  * (W_ * 64);
            const f16x4* hp1 = p0 + (size_t)h1 * (W_ * 64);
            for (int w = 0; w < nw; w += 4) {
                int w1 = (w + 1 < nw) ? w + 1 : w;
                int w2 = (w + 2 < nw) ? w + 2 : w;
                int w3 = (w + 3 < nw) ? w + 3 : w;
                a0 = max4h(a0, hp0[(size_t)w  * 64]);
                a1 = max4h(a1, hp0[(size_t)w1 * 64]);
                a2 = max4h(a2, hp0[(size_t)w2 * 64]);
                a3 = max4h(a3, hp0[(size_t)w3 * 64]);
                a4 = max4h(a4, hp1[(size_t)w  * 64]);
                a5 = max4h(a5, hp1[(size_t)w1 * 64]);
                a6 = max4h(a6, hp1[(size_t)w2 * 64]);
                a7 = max4h(a7, hp1[(size_t)w3 * 64]);
            }
        }
        f16x4 m = max4h(max4h(max4h(a0, a1), max4h(a2, a3)),
                        max4h(max4h(a4, a5), max4h(a6, a7)));

        stage[wv][4 * lane + 0] = (float)m[0];
        stage[wv][4 * lane + 1] = (float)m[1];
        stage[wv][4 * lane + 2] = (float)m[2];
        stage[wv][4 * lane + 3] = (float)m[3];
    }
    __syncthreads();

    float* dst = out + (size_t)n * C_ * NCELL + cg * 4;
    if (cg < 12) {
        #pragma unroll
        for (int k = 0; k < 4; ++k) {
            int f = threadIdx.x + 256 * k;
            int c = f >> 2, j = f & 3;
            dst[(size_t)c * NCELL + j] = stage[j][c];
        }
    } else {
        dst[(size_t)threadIdx.x * NCELL] = stage[0][threadIdx.x];
    }
}

__global__ __launch_bounds__(256) void roipool_direct_kernel(
    const float* __restrict__ feat, const float* __restrict__ rois,
    float* __restrict__ out, int total)
{
    int idx = blockIdx.x * blockDim.x + threadIdx.x;
    if (idx >= total) return;
    int pw = idx % POOLED;
    int ph = (idx / POOLED) % POOLED;
    int c  = (idx / (POOLED * POOLED)) % C_;
    int n  = idx / (POOLED * POOLED * C_);
    const float* r = rois + n * 5;
    int b  = (int)r[0];
    int x1 = (int)(r[1] * SCALE);
    int y1 = (int)(r[2] * SCALE);
    int x2 = (int)(r[3] * SCALE);
    int y2 = (int)(r[4] * SCALE);
    int rh = y2 - y1 + 1;
    int rw = x2 - x1 + 1;
    int hs = y1 + (ph * rh) / POOLED;
    int he = y1 + ((ph + 1) * rh + POOLED - 1) / POOLED;
    int ws = x1 + (pw * rw) / POOLED;
    int we = x1 + ((pw + 1) * rw + POOLED - 1) / POOLED;
    const float* plane = feat + ((size_t)b * C_ + c) * (size_t)S_;
    float m = -INFINITY;
    for (int h = hs; h < he; ++h) {
        const float* row = plane + h * W_;
        for (int w = ws; w < we; ++w) m = fmaxf(m, row[w]);
    }
    out[idx] = m;
}

extern "C" void kernel_launch(void* const* d_in, const int* in_sizes, int n_in,
                              void* d_out, int out_size, void* d_ws, size_t ws_size,
                              hipStream_t stream) {
    const float* feat = (const float*)d_in[0];
    const float* rois = (const float*)d_in[1];
    float* out = (float*)d_out;

    int N = in_sizes[1] / 5;
    size_t featBytes = (size_t)4 * S_ * C_ * sizeof(_Float16);   // 6.4 MB fp16 staging

    if (ws_size >= featBytes && N == 256) {
        _Float16* t = (_Float16*)d_ws;

        int maxB = 0;
        hipError_t qe = hipOccupancyMaxActiveBlocksPerMultiprocessor(
            &maxB, (const void*)fused_kernel, 256, 0);

        if (qe == hipSuccess && maxB > 0) {
            int grid = maxB * 256;           // co-resident bound (256 CUs)
            if (grid > 3328) grid = 3328;
            void* args[] = { (void*)&feat, (void*)&rois, (void*)&t, (void*)&out, (void*)&grid };
            hipError_t le = hipLaunchCooperativeKernel(
                (const void*)fused_kernel, dim3(grid), dim3(256), args, 0, stream);
            if (le == hipSuccess) return;
        }

        // fallback: proven R11 two-kernel path
        dim3 tgrid(S_ / 64, C_ / 64, 4);
        nhwc_kernel<<<tgrid, 1024, 0, stream>>>(feat, t);
        pool_fused_kernel<<<3328, 256, 0, stream>>>(t, rois, out);
    } else {
        int total = N * C_ * POOLED * POOLED;
        roipool_direct_kernel<<<(total + 255) / 256, 256, 0, stream>>>(feat, rois, out, total);
    }
}

// Round 13
// 30.693 us; speedup vs baseline: 4.6848x; 4.6848x over previous
//
#include <hip/hip_runtime.h>
#include <math.h>

#define POOLED 7
#define SCALE 0.0625f
#define C_ 256
#define H_ 56
#define W_ 56
#define S_ (H_ * W_)   // 3136
#define NCELL 49

typedef _Float16 f16x4 __attribute__((ext_vector_type(4)));
typedef _Float16 f16x8 __attribute__((ext_vector_type(8)));

__device__ __forceinline__ f16x8 max8h(f16x8 a, f16x8 b) {
    f16x8 r;
    #pragma unroll
    for (int i = 0; i < 8; ++i) r[i] = a[i] > b[i] ? a[i] : b[i];
    return r;
}

// ---------- Kernel 1: NCHW fp32 -> NHWC fp16 transpose ----------
// grid = (S/64, C/64, B), 1024 threads, 64x64 tile.
__global__ __launch_bounds__(1024) void nhwc_kernel(
    const float* __restrict__ src, _Float16* __restrict__ dst)
{
    __shared__ float tile[64][65];
    int b = blockIdx.z;
    int sbase = blockIdx.x * 64;
    int cbase = blockIdx.y * 64;
    int tid = threadIdx.x;

    const float* s0 = src + (size_t)b * C_ * S_;
    _Float16* d0 = dst + (size_t)b * S_ * C_;

    {
        int si = tid & 15;
        int c  = tid >> 4;
        float4 v = *(const float4*)(s0 + (size_t)(cbase + c) * S_ + sbase + 4 * si);
        tile[4 * si + 0][c] = v.x;
        tile[4 * si + 1][c] = v.y;
        tile[4 * si + 2][c] = v.z;
        tile[4 * si + 3][c] = v.w;
    }
    __syncthreads();
    {
        int cj = tid & 15;
        int s  = tid >> 4;
        f16x4 pk;
        pk[0] = (_Float16)tile[s][4 * cj + 0];
        pk[1] = (_Float16)tile[s][4 * cj + 1];
        pk[2] = (_Float16)tile[s][4 * cj + 2];
        pk[3] = (_Float16)tile[s][4 * cj + 3];
        *(f16x4*)(d0 + (size_t)(sbase + s) * C_ + cbase + 4 * cj) = pk;
    }
}

// ---------- Kernel 2: fused pool + output write, 2 positions per wave-load ----------
// grid = 3328 blocks (256 n x 13 cell-groups), 256 threads = 4 waves.
// Lane l: pos = l>>5 (0/1), c8 = l&31 (8 channels, f16x8 = 16B). One wave-load
// covers 2 spatial positions x 256 channels = 1KB fully-coalesced. Loads per
// cell ~ nh*nw/2 (was nh*nw). Cross-half combine via 4x shfl_xor(32) + max.
__global__ __launch_bounds__(256) void pool_fused_kernel(
    const _Float16* __restrict__ t, const float* __restrict__ rois,
    float* __restrict__ out)
{
    __shared__ float stage[4][257];
    int b0   = blockIdx.x;
    int swz  = (b0 & 7) * 416 + (b0 >> 3);   // bijective XCD chunking
    int n    = swz / 13;
    int cg   = swz % 13;
    int wv   = threadIdx.x >> 6;
    int lane = threadIdx.x & 63;
    int cell = cg * 4 + wv;

    const float* r = rois + n * 5;
    int b  = (int)r[0];
    int x1 = (int)(r[1] * SCALE);
    int y1 = (int)(r[2] * SCALE);
    int x2 = (int)(r[3] * SCALE);
    int y2 = (int)(r[4] * SCALE);
    int rh = y2 - y1 + 1;
    int rw = x2 - x1 + 1;

    if (cell < NCELL) {
        int ph = cell / POOLED;
        int pw = cell % POOLED;
        int hs = y1 + (ph * rh) / POOLED;
        int he = y1 + ((ph + 1) * rh + POOLED - 1) / POOLED;
        int ws = x1 + (pw * rw) / POOLED;
        int we = x1 + ((pw + 1) * rw + POOLED - 1) / POOLED;
        int nh = he - hs;
        int nw = we - ws;

        int pos = lane >> 5;       // 0 or 1
        int c8  = lane & 31;       // channel octet

        // f16x8 units: 32 per spatial position
        const f16x8* base = (const f16x8*)(t + (size_t)b * S_ * C_) + c8
                            + (size_t)(hs * W_ + ws) * 32;

        const _Float16 NEGV = (_Float16)(-65504.0f);
        f16x8 a0 = {NEGV, NEGV, NEGV, NEGV, NEGV, NEGV, NEGV, NEGV};
        f16x8 a1 = a0, a2 = a0, a3 = a0;

        for (int h = 0; h < nh; h += 2) {
            int h1 = (h + 1 < nh) ? h + 1 : h;
            const f16x8* hp0 = base + (size_t)h  * (W_ * 32);
            const f16x8* hp1 = base + (size_t)h1 * (W_ * 32);
            for (int w = 0; w < nw; w += 4) {
                int o0 = w + pos;     if (o0 >= nw) o0 = nw - 1;   // covers w, w+1
                int o1 = w + 2 + pos; if (o1 >= nw) o1 = nw - 1;   // covers w+2, w+3
                a0 = max8h(a0, hp0[(size_t)o0 * 32]);
                a1 = max8h(a1, hp0[(size_t)o1 * 32]);
                a2 = max8h(a2, hp1[(size_t)o0 * 32]);
                a3 = max8h(a3, hp1[(size_t)o1 * 32]);
            }
        }
        f16x8 m = max8h(max8h(a0, a1), max8h(a2, a3));

        // combine the two position-halves of the wave
        union { f16x8 h8; unsigned int u[4]; } A, B;
        A.h8 = m;
        #pragma unroll
        for (int k = 0; k < 4; ++k) B.u[k] = __shfl_xor(A.u[k], 32, 64);
        m = max8h(A.h8, B.h8);

        if (lane < 32) {
            #pragma unroll
            for (int j = 0; j < 8; ++j)
                stage[wv][8 * c8 + j] = (float)m[j];
        }
    }
    __syncthreads();

    float* dst = out + (size_t)n * C_ * NCELL + cg * 4;
    if (cg < 12) {
        #pragma unroll
        for (int k = 0; k < 4; ++k) {
            int f = threadIdx.x + 256 * k;
            int c = f >> 2, j = f & 3;
            dst[(size_t)c * NCELL + j] = stage[j][c];
        }
    } else {
        dst[(size_t)threadIdx.x * NCELL] = stage[0][threadIdx.x];
    }
}

// ---------- Fallback if workspace too small ----------
__global__ __launch_bounds__(256) void roipool_direct_kernel(
    const float* __restrict__ feat, const float* __restrict__ rois,
    float* __restrict__ out, int total)
{
    int idx = blockIdx.x * blockDim.x + threadIdx.x;
    if (idx >= total) return;
    int pw = idx % POOLED;
    int ph = (idx / POOLED) % POOLED;
    int c  = (idx / (POOLED * POOLED)) % C_;
    int n  = idx / (POOLED * POOLED * C_);
    const float* r = rois + n * 5;
    int b  = (int)r[0];
    int x1 = (int)(r[1] * SCALE);
    int y1 = (int)(r[2] * SCALE);
    int x2 = (int)(r[3] * SCALE);
    int y2 = (int)(r[4] * SCALE);
    int rh = y2 - y1 + 1;
    int rw = x2 - x1 + 1;
    int hs = y1 + (ph * rh) / POOLED;
    int he = y1 + ((ph + 1) * rh + POOLED - 1) / POOLED;
    int ws = x1 + (pw * rw) / POOLED;
    int we = x1 + ((pw + 1) * rw + POOLED - 1) / POOLED;
    const float* plane = feat + ((size_t)b * C_ + c) * (size_t)S_;
    float m = -INFINITY;
    for (int h = hs; h < he; ++h) {
        const float* row = plane + h * W_;
        for (int w = ws; w < we; ++w) m = fmaxf(m, row[w]);
    }
    out[idx] = m;
}

extern "C" void kernel_launch(void* const* d_in, const int* in_sizes, int n_in,
                              void* d_out, int out_size, void* d_ws, size_t ws_size,
                              hipStream_t stream) {
    const float* feat = (const float*)d_in[0];
    const float* rois = (const float*)d_in[1];
    float* out = (float*)d_out;

    int N = in_sizes[1] / 5;
    size_t featBytes = (size_t)4 * S_ * C_ * sizeof(_Float16);   // 6.4 MB fp16 staging

    if (ws_size >= featBytes && N == 256) {
        _Float16* t = (_Float16*)d_ws;

        dim3 tgrid(S_ / 64, C_ / 64, 4);
        nhwc_kernel<<<tgrid, 1024, 0, stream>>>(feat, t);

        pool_fused_kernel<<<3328, 256, 0, stream>>>(t, rois, out);
    } else {
        int total = N * C_ * POOLED * POOLED;
        roipool_direct_kernel<<<(total + 255) / 256, 256, 0, stream>>>(feat, rois, out, total);
    }
}